// Round 9
// baseline (2478.257 us; speedup 1.0000x reference)
//
#include <hip/hip_runtime.h>
#include <math.h>

// Problem constants (from reference)
#define B_   8
#define T_   128
#define E_   256
#define H_   512
#define G_   2048
#define NWG  256           // 1 WG per CU (LDS-forced), all co-resident
#define NTHR 512           // 8 waves; wave wv owns h-cols {s*16+2wv, +1}
#define XP   130           // Xl pitch in ushorts

typedef unsigned int u32;
typedef unsigned long long u64;

// ---------------------------------------------------------------------------
// ALGEBRA (unchanged): softmax over t sums to 1 and h_shared is t-invariant =>
// Rt == h_last; attention path dead. Per batch b (independent!):
//   h_last = sharedLSTM(emb[b]); M = h_last @ Wmh_t; out[b] = taskLSTM(...)
//
// R9 = R8 rings with a BARRIER-FREE step loop (R8 post-mortem: 2x
// __syncthreads + LDS h-stage + wave-0-only gates = ~1 us/step of WG-wide
// serialization). Wave = (b,s,wv) owns 8 gate-cols (4 gates x 2 h-cols),
// K=512 in 64 pinned VGPRs/lane. Per step, per wave, all in-registers:
//   poll own first u64 of h (8B narrow -> no MALL saturation), one-shot the
//   other 24B (in-band mantissa-LSB parity tags, validate+retry), 64 FMAs,
//   9-shuffle value-halving butterfly (full-K in-wave reduction), 4-shfl
//   gate gather, gates, 2 tagged publishes. No vmcnt drain, no flags.
// No-lap: wave publishes gen g+1 only after validating gen g; tag-valid g+1
// everywhere => all reads of g done => overwrite (g+2, opposite parity) safe.
// img: u32[2][8][512]; buf0 init tag0, buf1 init tag1.
// ---------------------------------------------------------------------------

__device__ __forceinline__ float sigf(float x) { return 1.0f / (1.0f + expf(-x)); }

__device__ __forceinline__ unsigned short f2bf(float x) {
  u32 u = __float_as_uint(x);
  u += 0x7fffu + ((u >> 16) & 1u);
  return (unsigned short)(u >> 16);
}
__device__ __forceinline__ float bf2f(unsigned short s) {
  return __uint_as_float(((u32)s) << 16);
}

__global__ void init_ws(u32* w) {
  int i = blockIdx.x * blockDim.x + threadIdx.x;
  if (i < 4096)      w[i] = 0u;   // buf0: tag 0
  else if (i < 8192) w[i] = 1u;   // buf1: tag 1
}

// Wave-clustered k-major slice: Wl[k*64 + (wv*8 + g*2 + u)] =
//   W[k][g*H + s*16 + wv*2 + u]   (so a wave's 8 cols are contiguous)
__device__ __forceinline__ void stage_W(const float* __restrict__ W, int rows,
                                        int s, float* __restrict__ Wl) {
  for (int idx = threadIdx.x; idx < rows * 64; idx += NTHR) {
    int k = idx >> 6, c = idx & 63;
    int wv = c >> 3, g = (c >> 1) & 3, u = c & 1;
    Wl[idx] = W[k * G_ + g * H_ + s * 16 + wv * 2 + u];
  }
}

__attribute__((amdgpu_waves_per_eu(2)))
__global__ __launch_bounds__(NTHR, 1) void lstm_all(
    const int* __restrict__ tokens, const float* __restrict__ embed,
    const float* __restrict__ Wih_s, const float* __restrict__ Whh_s,
    const float* __restrict__ b_s,
    const float* __restrict__ Wih_t, const float* __restrict__ Whh_t,
    const float* __restrict__ Wmh_t, const float* __restrict__ b_t,
    float* __restrict__ out, u32* __restrict__ img) {
  __shared__ float Wl[H_ * 64];             // 128 KB k-major weight slice
  __shared__ unsigned short Xl[64 * XP];    // 16.25 KB bf16 X[c_local][t]

  const int tid = threadIdx.x;
  const int l   = tid & 63;                 // lane
  const int wv  = tid >> 6;                 // wave -> h-cols s*16+2wv, +1
  const int b   = blockIdx.x & 7;           // ring = batch
  const int s   = blockIdx.x >> 3;          // slot -> h-cols 16s..16s+15

  // lane's owned col after butterfly: c8 = g*2+u
  const int c8  = ((l & 1) << 2) | (l & 2) | ((l >> 2) & 1);
  const int g_  = c8 >> 1, u_ = c8 & 1;
  const int xcol = g_ * 16 + wv * 2 + u_;   // own col's Xl row
  // gate-gather source lanes: col 2g'+u_ sits at lane (l&~7)|m(2g'+u_), m=c8 map
  auto mmap = [](int x) { return ((x & 1) << 2) | (x & 2) | ((x >> 2) & 1); };
  const int base8 = l & ~7;
  const int sg0 = base8 | mmap(0 + u_);
  const int sg1 = base8 | mmap(2 + u_);
  const int sg2 = base8 | mmap(4 + u_);
  const int sg3 = base8 | mmap(6 + u_);
  const bool st = (l == 0) || (l == 4);     // publish lanes (u = l>>2)
  const int jcol = s * 16 + wv * 2 + (l >> 2);

  float wreg[64];                           // pinned: W[l*8..+8)[8 own cols]

  auto load_wreg = [&]() {
#pragma unroll
    for (int kk = 0; kk < 8; ++kk) {
      const float4* p = (const float4*)(Wl + (l * 8 + kk) * 64 + wv * 8);
      float4 a = p[0], q = p[1];
      wreg[kk * 8 + 0] = a.x; wreg[kk * 8 + 1] = a.y;
      wreg[kk * 8 + 2] = a.z; wreg[kk * 8 + 3] = a.w;
      wreg[kk * 8 + 4] = q.x; wreg[kk * 8 + 5] = q.y;
      wreg[kk * 8 + 6] = q.z; wreg[kk * 8 + 7] = q.w;
    }
#pragma unroll
    for (int i = 0; i < 64; ++i) asm volatile("" : "+v"(wreg[i]));  // pin
  };

  // poll + payload + dot + butterfly: returns own-col (c8) full-K sum
  auto rec_dot = [&](unsigned gen) -> float {
    const u32 par = (gen >> 1) & 1u;
    const u64* src = (const u64*)(img + (size_t)(gen & 1u) * 4096 + b * H_)
                     + (size_t)l * 4;
    u64 v0;
    for (;;) {                              // narrow poll: 8 B/lane/round
      v0 = __hip_atomic_load(src, __ATOMIC_RELAXED, __HIP_MEMORY_SCOPE_AGENT);
      if (!((((u32)v0 ^ par) | ((u32)(v0 >> 32) ^ par)) & 1u)) break;
      __builtin_amdgcn_s_sleep(1);
    }
    u64 v1, v2, v3;
    for (;;) {                              // one-shot 24 B + validate
      v1 = __hip_atomic_load(src + 1, __ATOMIC_RELAXED, __HIP_MEMORY_SCOPE_AGENT);
      v2 = __hip_atomic_load(src + 2, __ATOMIC_RELAXED, __HIP_MEMORY_SCOPE_AGENT);
      v3 = __hip_atomic_load(src + 3, __ATOMIC_RELAXED, __HIP_MEMORY_SCOPE_AGENT);
      u32 bad = ((u32)v1 ^ par) | ((u32)(v1 >> 32) ^ par) |
                ((u32)v2 ^ par) | ((u32)(v2 >> 32) ^ par) |
                ((u32)v3 ^ par) | ((u32)(v3 >> 32) ^ par);
      if (!(bad & 1u)) break;
      __builtin_amdgcn_s_sleep(1);
    }
    float h8[8];
    h8[0] = __uint_as_float((u32)v0); h8[1] = __uint_as_float((u32)(v0 >> 32));
    h8[2] = __uint_as_float((u32)v1); h8[3] = __uint_as_float((u32)(v1 >> 32));
    h8[4] = __uint_as_float((u32)v2); h8[5] = __uint_as_float((u32)(v2 >> 32));
    h8[6] = __uint_as_float((u32)v3); h8[7] = __uint_as_float((u32)(v3 >> 32));

    float acc[8];
#pragma unroll
    for (int c = 0; c < 8; ++c) acc[c] = 0.0f;
#pragma unroll
    for (int kk = 0; kk < 8; ++kk) {
      float hv = h8[kk];
#pragma unroll
      for (int c = 0; c < 8; ++c) acc[c] += hv * wreg[kk * 8 + c];
    }
    float o4[4];
#pragma unroll
    for (int j = 0; j < 4; ++j) {
      float send = (l & 1) ? acc[j] : acc[4 + j];
      float keep = (l & 1) ? acc[4 + j] : acc[j];
      o4[j] = keep + __shfl_xor(send, 1);
    }
    float o2[2];
#pragma unroll
    for (int j = 0; j < 2; ++j) {
      float send = (l & 2) ? o4[j] : o4[2 + j];
      float keep = (l & 2) ? o4[2 + j] : o4[j];
      o2[j] = keep + __shfl_xor(send, 2);
    }
    float send = (l & 4) ? o2[0] : o2[1];
    float keep = (l & 4) ? o2[1] : o2[0];
    float sum = keep + __shfl_xor(send, 4);
    sum += __shfl_xor(sum, 8);
    sum += __shfl_xor(sum, 16);
    sum += __shfl_xor(sum, 32);
    return sum;
  };

  // Xl[c_local][t] (bf16) = emb[b,t] @ Wih[:,col] + bias[col]
  auto computeX = [&](const float* __restrict__ Wih, const float* __restrict__ bias) {
    stage_W(Wih, E_, s, Wl);
    __syncthreads();
    const int t = tid >> 2, grp = tid & 3;
    const int tok = tokens[b * T_ + t];
    const float4* er = (const float4*)(embed + (size_t)tok * E_);
    float acc[16];
#pragma unroll
    for (int j = 0; j < 16; ++j) acc[j] = bias[grp * H_ + s * 16 + j];
    for (int e4 = 0; e4 < E_ / 4; ++e4) {
      float4 em = er[e4];
#pragma unroll
      for (int eo = 0; eo < 4; ++eo) {
        float ev = reinterpret_cast<const float*>(&em)[eo];
        const float* wr = Wl + (e4 * 4 + eo) * 64;
#pragma unroll
        for (int j = 0; j < 16; ++j)
          acc[j] += ev * wr[(j >> 1) * 8 + grp * 2 + (j & 1)];  // 4 addrs: bcast
      }
    }
#pragma unroll
    for (int j = 0; j < 16; ++j) Xl[(grp * 16 + j) * XP + t] = f2bf(acc[j]);
  };

  auto gates = [&](float pre, float& c_reg) -> float {
    float pi = __shfl(pre, sg0), pf = __shfl(pre, sg1);
    float pg = __shfl(pre, sg2), po = __shfl(pre, sg3);
    float cn = sigf(pf) * c_reg + sigf(pi) * tanhf(pg);
    float hn = sigf(po) * tanhf(cn);
    c_reg = cn;
    return hn;
  };

  // ---------------- Phase A1 + shared weights
  computeX(Wih_s, b_s);
  __syncthreads();
  stage_W(Whh_s, H_, s, Wl);
  __syncthreads();
  load_wreg();

  // ---------------- Phase B: shared LSTM; publishes gens 1..128
  float c_reg = 0.0f;
  for (int t = 0; t < T_; ++t) {
    float S = (t > 0) ? rec_dot((unsigned)t) : 0.0f;
    float pre = S + bf2f(Xl[xcol * XP + t]);
    float hn = gates(pre, c_reg);
    const unsigned gw = (unsigned)t + 1u;
    if (st) {
      u32 hb = (__float_as_uint(hn) & ~1u) | ((gw >> 1) & 1u);
      __hip_atomic_store(img + (gw & 1u) * 4096 + b * H_ + jcol, hb,
                         __ATOMIC_RELAXED, __HIP_MEMORY_SCOPE_AGENT);
    }
  }

  // ---------------- M = h_last @ Wmh_t (consume gen 128)
  __syncthreads();
  stage_W(Wmh_t, H_, s, Wl);
  __syncthreads();
  load_wreg();
  float Mreg = rec_dot(128u);

  // ---------------- Phase A2 + task weights
  __syncthreads();
  computeX(Wih_t, b_t);
  __syncthreads();
  stage_W(Whh_t, H_, s, Wl);
  __syncthreads();
  load_wreg();

  // ---------------- Phase C: task LSTM; gens 129..255; out every step
  c_reg = 0.0f;
  for (int t = 0; t < T_; ++t) {
    float S = (t > 0) ? rec_dot(128u + (unsigned)t) : 0.0f;
    float pre = S + bf2f(Xl[xcol * XP + t]) + Mreg;
    float hn = gates(pre, c_reg);
    if (st) {
      out[b * (T_ * H_) + t * H_ + jcol] = hn;
      if (t < T_ - 1) {
        const unsigned gw = 129u + (unsigned)t;
        u32 hb = (__float_as_uint(hn) & ~1u) | ((gw >> 1) & 1u);
        __hip_atomic_store(img + (gw & 1u) * 4096 + b * H_ + jcol, hb,
                           __ATOMIC_RELAXED, __HIP_MEMORY_SCOPE_AGENT);
      }
    }
  }
}

extern "C" void kernel_launch(void* const* d_in, const int* in_sizes, int n_in,
                              void* d_out, int out_size, void* d_ws, size_t ws_size,
                              hipStream_t stream) {
  const int*   tokens = (const int*)d_in[0];
  // d_in[1] = TASK (unused)
  const float* embed  = (const float*)d_in[2];
  const float* Wih_s  = (const float*)d_in[3];
  const float* Whh_s  = (const float*)d_in[4];
  const float* b_s    = (const float*)d_in[5];
  // d_in[6..9] = Ws_w, Ws_b, Us_w, Us_b -> dead (attention collapses)
  const float* Wih_t  = (const float*)d_in[10];
  const float* Whh_t  = (const float*)d_in[11];
  const float* Wmh_t  = (const float*)d_in[12];
  const float* b_t    = (const float*)d_in[13];
  float* out = (float*)d_out;
  u32*   img = (u32*)d_ws;

  hipLaunchKernelGGL(init_ws, dim3(8), dim3(1024), 0, stream, img);
  hipLaunchKernelGGL(lstm_all, dim3(NWG), dim3(NTHR), 0, stream,
                     tokens, embed, Wih_s, Whh_s, b_s,
                     Wih_t, Whh_t, Wmh_t, b_t, out, img);
}

// Round 10
// 984.002 us; speedup vs baseline: 2.5185x; 2.5185x over previous
//
#include <hip/hip_runtime.h>
#include <math.h>

// Problem constants (from reference)
#define B_   8
#define T_   128
#define E_   256
#define H_   512
#define G_   2048
#define NWG  256           // 1 WG per CU (LDS-forced), all co-resident
#define NTHR 512           // 8 waves
#define XP   130           // Xl pitch in ushorts
#define HP   640           // padded h-image u32s per parity buffer (8 floats -> 10 slots)

typedef unsigned int u32;
typedef unsigned long long u64;

// ---------------------------------------------------------------------------
// ALGEBRA (unchanged): softmax over t sums to 1 and h_shared is t-invariant =>
// Rt == h_last; attention path dead. Per batch b (independent):
//   h_last = sharedLSTM(emb[b]); M = h_last @ Wmh_t; out[b] = taskLSTM(...)
//
// R10 = R8's exchange traffic + R9's register compute, coupled by a
// tag-validated LDS handoff instead of barriers:
//  - 8 rings of 32 WGs (ring = blockIdx&7 = batch, slot = blockIdx>>3).
//  - MALL img: u32[2][8][512], in-band mantissa-LSB parity tag (gen>>1)&1.
//    Thread tid polls ONLY its own float (4B) -> h read exactly once per WG
//    per step (R8 invariant; R3/R9 died on redundant reads), ds-stores it
//    (tag intact) into a parity-double-buffered padded LDS image.
//  - Lane l of each wave tag-poll-reads its 8 floats (k=l*8..+8) from LDS
//    (4x ds_read_b64, pad-swizzled: float k at u32 slot k+2*(k>>3) -> b64s
//    land on distinct banks). No __syncthreads in the step loop: LDS tags
//    carry the dependency. Buffer-reuse safety: validating gen g+1 implies
//    every wave of every WG finished step g, hence finished reading buffer
//    (g-1)&1 = (g+1)&1 before anyone stages gen g+1 into it.
//  - Dot in registers: 64 pinned weight VGPRs/lane (asm "+v" — the only
//    thing that stops the allocator from rematerializing, per R4-R7),
//    64 FMAs, 9-shuffle value-halving butterfly, 4-shfl gate gather,
//    2 publish lanes per wave. X staged bf16 in LDS.
// ---------------------------------------------------------------------------

__device__ __forceinline__ float sigf(float x) { return 1.0f / (1.0f + expf(-x)); }

__device__ __forceinline__ unsigned short f2bf(float x) {
  u32 u = __float_as_uint(x);
  u += 0x7fffu + ((u >> 16) & 1u);
  return (unsigned short)(u >> 16);
}
__device__ __forceinline__ float bf2f(unsigned short s) {
  return __uint_as_float(((u32)s) << 16);
}

__global__ void init_ws(u32* w) {
  int i = blockIdx.x * blockDim.x + threadIdx.x;
  if (i < 4096)      w[i] = 0u;   // buf0: tag 0 (first use gen2, parity 1 -> reject)
  else if (i < 8192) w[i] = 1u;   // buf1: tag 1 (first use gen1, parity 0 -> reject)
}

// Wave-clustered k-major slice: Wl[k*64 + (wv*8 + g*2 + u)] =
//   W[k][g*H + s*16 + wv*2 + u]   (a wave's 8 cols are contiguous)
__device__ __forceinline__ void stage_W(const float* __restrict__ W, int rows,
                                        int s, float* __restrict__ Wl) {
  for (int idx = threadIdx.x; idx < rows * 64; idx += NTHR) {
    int k = idx >> 6, c = idx & 63;
    int wv = c >> 3, g = (c >> 1) & 3, u = c & 1;
    Wl[idx] = W[k * G_ + g * H_ + s * 16 + wv * 2 + u];
  }
}

__attribute__((amdgpu_waves_per_eu(2)))
__global__ __launch_bounds__(NTHR, 1) void lstm_all(
    const int* __restrict__ tokens, const float* __restrict__ embed,
    const float* __restrict__ Wih_s, const float* __restrict__ Whh_s,
    const float* __restrict__ b_s,
    const float* __restrict__ Wih_t, const float* __restrict__ Whh_t,
    const float* __restrict__ Wmh_t, const float* __restrict__ b_t,
    float* __restrict__ out, u32* __restrict__ img) {
  __shared__ float Wl[H_ * 64];             // 128 KB k-major weight slice
  __shared__ unsigned short Xl[64 * XP];    // 16.25 KB bf16 X[c_local][t]
  __shared__ u64 h64[HP];                   // 5 KB: 2 parity buffers, padded

  const int tid = threadIdx.x;
  const int l   = tid & 63;                 // lane
  const int wv  = tid >> 6;                 // wave -> h-cols s*16+2wv, +1
  const int b   = blockIdx.x & 7;           // ring = batch
  const int s   = blockIdx.x >> 3;          // slot -> h-cols 16s..16s+15

  // lane's owned col after butterfly: c8 = g*2+u
  const int c8  = ((l & 1) << 2) | (l & 2) | ((l >> 2) & 1);
  const int u_  = c8 & 1;
  const int g_  = c8 >> 1;
  const int xcol = g_ * 16 + wv * 2 + u_;
  auto mmap = [](int x) { return ((x & 1) << 2) | (x & 2) | ((x >> 2) & 1); };
  const int base8 = l & ~7;
  const int sg0 = base8 | mmap(0 + u_);
  const int sg1 = base8 | mmap(2 + u_);
  const int sg2 = base8 | mmap(4 + u_);
  const int sg3 = base8 | mmap(6 + u_);
  const bool st = (l == 0) || (l == 4);     // publish lanes (u = l>>2)
  const int jcol = s * 16 + wv * 2 + (l >> 2);

  float wreg[64];                           // pinned: W[l*8..+8)[wave's 8 cols]

  auto load_wreg = [&]() {
#pragma unroll
    for (int kk = 0; kk < 8; ++kk) {
      const float4* p = (const float4*)(Wl + (l * 8 + kk) * 64 + wv * 8);
      float4 a = p[0], q = p[1];
      wreg[kk * 8 + 0] = a.x; wreg[kk * 8 + 1] = a.y;
      wreg[kk * 8 + 2] = a.z; wreg[kk * 8 + 3] = a.w;
      wreg[kk * 8 + 4] = q.x; wreg[kk * 8 + 5] = q.y;
      wreg[kk * 8 + 6] = q.z; wreg[kk * 8 + 7] = q.w;
    }
#pragma unroll
    for (int i = 0; i < 64; ++i) asm volatile("" : "+v"(wreg[i]));  // pin
  };

  // MALL poll own float -> LDS stage -> LDS tag-poll own 8 floats -> dot ->
  // butterfly. Returns own-col (c8) full-K sum.
  auto rec_dot = [&](unsigned gen) -> float {
    const u32 par = (gen >> 1) & 1u;
    const u32 bsel = gen & 1u;
    {                                        // 1) MALL poll (4 B, own float)
      const u32* src = img + (size_t)bsel * 4096 + b * H_ + tid;
      u32 u;
      while (((u = __hip_atomic_load(src, __ATOMIC_RELAXED,
                                     __HIP_MEMORY_SCOPE_AGENT)) & 1u) != par)
        __builtin_amdgcn_s_sleep(1);
      volatile u32* dst = (volatile u32*)h64;
      dst[bsel * HP + tid + 2 * (tid >> 3)] = u;   // pad-swizzled stage
    }
    // 2) LDS tag-poll of lane's 8 floats (k = l*8..+8)
    volatile u64* hl = (volatile u64*)h64 + (size_t)bsel * (HP / 2) + (size_t)l * 5;
    u64 w0, w1, w2, w3;
    for (;;) {
      w0 = hl[0]; w1 = hl[1]; w2 = hl[2]; w3 = hl[3];
      u32 bad = ((u32)w0 ^ par) | ((u32)(w0 >> 32) ^ par) |
                ((u32)w1 ^ par) | ((u32)(w1 >> 32) ^ par) |
                ((u32)w2 ^ par) | ((u32)(w2 >> 32) ^ par) |
                ((u32)w3 ^ par) | ((u32)(w3 >> 32) ^ par);
      if (!(bad & 1u)) break;
    }
    float h8[8];
    h8[0] = __uint_as_float((u32)w0); h8[1] = __uint_as_float((u32)(w0 >> 32));
    h8[2] = __uint_as_float((u32)w1); h8[3] = __uint_as_float((u32)(w1 >> 32));
    h8[4] = __uint_as_float((u32)w2); h8[5] = __uint_as_float((u32)(w2 >> 32));
    h8[6] = __uint_as_float((u32)w3); h8[7] = __uint_as_float((u32)(w3 >> 32));

    float acc[8];
#pragma unroll
    for (int c = 0; c < 8; ++c) acc[c] = 0.0f;
#pragma unroll
    for (int kk = 0; kk < 8; ++kk) {
      float hv = h8[kk];
#pragma unroll
      for (int c = 0; c < 8; ++c) acc[c] += hv * wreg[kk * 8 + c];
    }
    float o4[4];
#pragma unroll
    for (int j = 0; j < 4; ++j) {
      float send = (l & 1) ? acc[j] : acc[4 + j];
      float keep = (l & 1) ? acc[4 + j] : acc[j];
      o4[j] = keep + __shfl_xor(send, 1);
    }
    float o2[2];
#pragma unroll
    for (int j = 0; j < 2; ++j) {
      float send = (l & 2) ? o4[j] : o4[2 + j];
      float keep = (l & 2) ? o4[2 + j] : o4[j];
      o2[j] = keep + __shfl_xor(send, 2);
    }
    float send = (l & 4) ? o2[0] : o2[1];
    float keep = (l & 4) ? o2[1] : o2[0];
    float sum = keep + __shfl_xor(send, 4);
    sum += __shfl_xor(sum, 8);
    sum += __shfl_xor(sum, 16);
    sum += __shfl_xor(sum, 32);
    return sum;
  };

  // Xl[c_local][t] (bf16) = emb[b,t] @ Wih[:,col] + bias[col]
  auto computeX = [&](const float* __restrict__ Wih, const float* __restrict__ bias) {
    stage_W(Wih, E_, s, Wl);
    __syncthreads();
    const int t = tid >> 2, grp = tid & 3;
    const int tok = tokens[b * T_ + t];
    const float4* er = (const float4*)(embed + (size_t)tok * E_);
    float acc[16];
#pragma unroll
    for (int j = 0; j < 16; ++j) acc[j] = bias[grp * H_ + s * 16 + j];
    for (int e4 = 0; e4 < E_ / 4; ++e4) {
      float4 em = er[e4];
#pragma unroll
      for (int eo = 0; eo < 4; ++eo) {
        float ev = reinterpret_cast<const float*>(&em)[eo];
        const float* wr = Wl + (e4 * 4 + eo) * 64;
#pragma unroll
        for (int j = 0; j < 16; ++j)
          acc[j] += ev * wr[(j >> 1) * 8 + grp * 2 + (j & 1)];
      }
    }
#pragma unroll
    for (int j = 0; j < 16; ++j) Xl[(grp * 16 + j) * XP + t] = f2bf(acc[j]);
  };

  auto gates = [&](float pre, float& c_reg) -> float {
    float pi = __shfl(pre, sg0), pf = __shfl(pre, sg1);
    float pg = __shfl(pre, sg2), po = __shfl(pre, sg3);
    float cn = sigf(pf) * c_reg + sigf(pi) * tanhf(pg);
    float hn = sigf(po) * tanhf(cn);
    c_reg = cn;
    return hn;
  };

  auto publish = [&](float hn, unsigned gw) {
    if (st) {
      u32 hb = (__float_as_uint(hn) & ~1u) | ((gw >> 1) & 1u);
      __hip_atomic_store(img + (size_t)(gw & 1u) * 4096 + b * H_ + jcol, hb,
                         __ATOMIC_RELAXED, __HIP_MEMORY_SCOPE_AGENT);
    }
  };

  // init LDS h image to tagged-invalid (uninitialized LDS could false-pass)
  {
    volatile u32* hp = (volatile u32*)h64;
    for (int i = tid; i < 2 * HP; i += NTHR) hp[i] = (i < HP) ? 0u : 1u;
  }

  // ---------------- Phase A1 + shared weights
  computeX(Wih_s, b_s);
  __syncthreads();
  stage_W(Whh_s, H_, s, Wl);
  __syncthreads();
  load_wreg();

  // ---------------- Phase B: shared LSTM; publishes gens 1..128
  float c_reg = 0.0f;
  for (int t = 0; t < T_; ++t) {
    float S = (t > 0) ? rec_dot((unsigned)t) : 0.0f;
    float pre = S + bf2f(Xl[xcol * XP + t]);
    float hn = gates(pre, c_reg);
    publish(hn, (unsigned)t + 1u);
  }

  // ---------------- M = h_last @ Wmh_t (consume gen 128)
  __syncthreads();
  stage_W(Wmh_t, H_, s, Wl);
  __syncthreads();
  load_wreg();
  float Mreg = rec_dot(128u);

  // ---------------- Phase A2 + task weights
  __syncthreads();
  computeX(Wih_t, b_t);
  __syncthreads();
  stage_W(Whh_t, H_, s, Wl);
  __syncthreads();
  load_wreg();

  // ---------------- Phase C: task LSTM; gens 129..255; out every step
  c_reg = 0.0f;
  for (int t = 0; t < T_; ++t) {
    float S = (t > 0) ? rec_dot(128u + (unsigned)t) : 0.0f;
    float pre = S + bf2f(Xl[xcol * XP + t]) + Mreg;
    float hn = gates(pre, c_reg);
    if (st) out[b * (T_ * H_) + t * H_ + jcol] = hn;
    if (t < T_ - 1) publish(hn, 129u + (unsigned)t);
  }
}

extern "C" void kernel_launch(void* const* d_in, const int* in_sizes, int n_in,
                              void* d_out, int out_size, void* d_ws, size_t ws_size,
                              hipStream_t stream) {
  const int*   tokens = (const int*)d_in[0];
  // d_in[1] = TASK (unused)
  const float* embed  = (const float*)d_in[2];
  const float* Wih_s  = (const float*)d_in[3];
  const float* Whh_s  = (const float*)d_in[4];
  const float* b_s    = (const float*)d_in[5];
  // d_in[6..9] = Ws_w, Ws_b, Us_w, Us_b -> dead (attention collapses)
  const float* Wih_t  = (const float*)d_in[10];
  const float* Whh_t  = (const float*)d_in[11];
  const float* Wmh_t  = (const float*)d_in[12];
  const float* b_t    = (const float*)d_in[13];
  float* out = (float*)d_out;
  u32*   img = (u32*)d_ws;

  hipLaunchKernelGGL(init_ws, dim3(8), dim3(1024), 0, stream, img);
  hipLaunchKernelGGL(lstm_all, dim3(NWG), dim3(NTHR), 0, stream,
                     tokens, embed, Wih_s, Whh_s, b_s,
                     Wih_t, Whh_t, Wmh_t, b_t, out, img);
}